// Round 3
// baseline (126.020 us; speedup 1.0000x reference)
//
#include <hip/hip_runtime.h>

// LogSignature depth-4, C=16, B=64, L=256, fp32.
// out per batch: [lvl1(16) | lvl2(256) | lvl3(4096) | lvl4(65536)] = 69904
// ws layout (floats):
//   dx1 [j][256][16] : time-major, padded to 256 steps (t=255 = zero step);
//                      read via address_space(4) -> s_load_dwordx16 (wave-uniform)
//   dxt [j][16][256] : component-major, per-lane float4 streams
//   sig123 [j][4368]
// zero step is mathematically the Chen identity (all updates scale by dx).

#define NC 16
#define NL 256
#define NB 64
#define NSTEP 255
#define NT 256
#define OUTB 69904
#define SIG123 4368
#define OFF_L2 16
#define OFF_L3 272
#define OFF_L4 4368

#define DX1_STRIDE (NT * NC)                  // 4096 floats per batch
#define DXT_OFF (NB * DX1_STRIDE)             // 262144
#define SIG_OFF (DXT_OFF + NB * NC * NT)      // 524288

typedef float vfloat16 __attribute__((ext_vector_type(16)));
typedef const __attribute__((address_space(4))) vfloat16* crow_ptr;
typedef const __attribute__((address_space(4))) float* cflt_ptr;

// One block per batch j: stage path[j] (16 KB) in LDS, emit both dx layouts.
__global__ __launch_bounds__(256) void k_dx(const float* __restrict__ path,
                                            float* __restrict__ dx1,
                                            float* __restrict__ dxt) {
    const int j = blockIdx.x;
    const int tid = threadIdx.x;
    __shared__ float L[NL * NC];  // 16 KB, [t][i]

    const float* pj = path + (size_t)j * NL * NC;
#pragma unroll
    for (int k = 0; k < 4; ++k) {
        const int f = tid + k * 256;
        *(float4*)&L[f * 4] = *(const float4*)&pj[f * 4];
    }
    __syncthreads();

    // time-major diffs (coalesced), zero-pad step 255
    float* d1 = dx1 + (size_t)j * DX1_STRIDE;
    for (int f = tid; f < NT * NC; f += 256)
        d1[f] = (f < NSTEP * NC) ? (L[f + NC] - L[f]) : 0.f;

    // component-major diffs: iter k = component, lane = t; zero-pad t=255
    float* dt = dxt + (size_t)j * NC * NT;
#pragma unroll
    for (int k = 0; k < NC; ++k) {
        const int t = tid;
        dt[k * 256 + t] = (t < NSTEP) ? (L[(t + 1) * NC + k] - L[t * NC + k]) : 0.f;
    }
}

// One block per (batch j, first-index a). Thread (b,c) owns s3[a,b,c] and
// s4[a,b,c,0..15] in registers; s1[a], s2[a,b] maintained redundantly.
// Row dx[t][0..15] comes in via SGPRs (s_load_dwordx16, scalar pipe).
__global__ __launch_bounds__(256, 4) void k_scan(const float* __restrict__ dx1,
                                                 const float* __restrict__ dxt,
                                                 float* __restrict__ out,
                                                 float* __restrict__ sig123) {
    const int bid = blockIdx.x;
    const int j = bid >> 4;
    const int a = bid & 15;
    const int tid = threadIdx.x;
    const int b = tid >> 4;
    const int c = tid & 15;

    float s4[16];
#pragma unroll
    for (int d = 0; d < 16; ++d) s4[d] = 0.f;
    float s3 = 0.f, s2ab = 0.f, s1a = 0.f;

    crow_ptr srow = (crow_ptr)(dx1 + (size_t)j * DX1_STRIDE);
    cflt_ptr sflt = (cflt_ptr)(dx1 + (size_t)j * DX1_STRIDE);
    const float* rb = dxt + ((size_t)j * NC + b) * NT;  // per-lane stream
    const float* rc = dxt + ((size_t)j * NC + c) * NT;

    float4 vb = *(const float4*)rb;
    float4 vc = *(const float4*)rc;

    for (int it = 0; it < 64; ++it) {
        const int nit = (it + 1) & 63;  // wrap: last prefetch reads valid mem, unused
        const float4 nvb = *(const float4*)(rb + 4 * nit);
        const float4 nvc = *(const float4*)(rc + 4 * nit);
#pragma unroll
        for (int u = 0; u < 4; ++u) {
            const int t = it * 4 + u;
            const vfloat16 w = srow[t];          // s_load_dwordx16 (uniform)
            const float dxa = sflt[t * 16 + a];  // s_load_dword (uniform)
            const float dxb = (u == 0) ? vb.x : (u == 1) ? vb.y : (u == 2) ? vb.z : vb.w;
            const float dxc = (u == 0) ? vc.x : (u == 1) ? vc.y : (u == 2) ? vc.z : vc.w;

            // T = s3 + dxc*(s2ab/2 + s1a*dxb/6 + dxa*dxb/24)   (old values)
            const float pre4 = fmaf(dxb, fmaf(1.f / 6.f, s1a, (1.f / 24.f) * dxa), 0.5f * s2ab);
            const float T = fmaf(dxc, pre4, s3);
#pragma unroll
            for (int d = 0; d < 16; ++d) s4[d] = fmaf(w[d], T, s4[d]);

            const float U = fmaf(dxb, fmaf(0.5f, s1a, (1.f / 6.f) * dxa), s2ab);
            s3 = fmaf(dxc, U, s3);
            s2ab = fmaf(dxb, fmaf(0.5f, dxa, s1a), s2ab);
            s1a += dxa;
        }
        vb = nvb;
        vc = nvc;
    }

    // epilogue: stage s4 slice in LDS, write block's contiguous 16 KB coalesced
    __shared__ float ls[4096];
#pragma unroll
    for (int d = 0; d < 16; d += 4)
        *(float4*)&ls[tid * 16 + d] = make_float4(s4[d], s4[d + 1], s4[d + 2], s4[d + 3]);
    __syncthreads();

    float* o4 = out + (size_t)j * OUTB + OFF_L4 + a * 4096;
#pragma unroll
    for (int k = 0; k < 4; ++k) {
        const int f = tid + k * 256;
        *(float4*)(o4 + f * 4) = *(const float4*)&ls[f * 4];
    }

    float* sg = sig123 + (size_t)j * SIG123;
    sg[OFF_L3 + (a * 16 + b) * 16 + c] = s3;
    if (c == 0) sg[OFF_L2 + a * 16 + b] = s2ab;
    if (tid == 0) sg[a] = s1a;
}

// log of signature. Block (j,a); level-4 slice coalesced float4 RMW.
// res4[a,b,c,d] = s4 - 1/2(s1a*s3[bcd] + s2ab*s2[cd] + s3abc*s1[d])
//                    + 1/3(s1a*s1b*s2[cd] + s1a*s2bc*s1[d] + s2ab*s1c*s1[d])
//                    - 1/4 s1a*s1b*s1c*s1[d]
__global__ __launch_bounds__(256) void k_log(const float* __restrict__ sig123,
                                             float* __restrict__ out) {
    const int bid = blockIdx.x;
    const int j = bid >> 4;
    const int a = bid & 15;
    const int tid = threadIdx.x;

    const float* sg = sig123 + (size_t)j * SIG123;
    const float* s1 = sg;
    const float* s2 = sg + OFF_L2;
    const float* s3 = sg + OFF_L3;

    const float s1a = s1[a];
    float* outj = out + (size_t)j * OUTB;
    float* o4 = outj + OFF_L4 + a * 4096;
    const float A = -0.5f * s1a;

#pragma unroll
    for (int k = 0; k < 4; ++k) {
        const int f = tid + k * 256;   // float4 index within slice
        const int m0 = f * 4;          // element offset: b*256 + c*16 + d0
        const int b = m0 >> 8;
        const int c = (m0 >> 4) & 15;
        const float s1b = s1[b], s1c = s1[c];
        const float s2ab = s2[a * 16 + b];
        const float s2bc = s2[b * 16 + c];
        const float s3abc = s3[(a * 16 + b) * 16 + c];

        const float Bv = fmaf((1.f / 3.f) * s1a, s1b, -0.5f * s2ab);
        const float Cv = -0.5f * s3abc + (1.f / 3.f) * fmaf(s1a, s2bc, s2ab * s1c)
                         - 0.25f * s1a * s1b * s1c;

        const float4 v4 = *(const float4*)(o4 + m0);
        const float4 v3 = *(const float4*)(s3 + m0);
        const float4 v2 = *(const float4*)(s2 + (m0 & 255));
        const float4 v1 = *(const float4*)(s1 + (m0 & 15));
        float4 rr;
        rr.x = fmaf(A, v3.x, v4.x) + fmaf(Bv, v2.x, Cv * v1.x);
        rr.y = fmaf(A, v3.y, v4.y) + fmaf(Bv, v2.y, Cv * v1.y);
        rr.z = fmaf(A, v3.z, v4.z) + fmaf(Bv, v2.z, Cv * v1.z);
        rr.w = fmaf(A, v3.w, v4.w) + fmaf(Bv, v2.w, Cv * v1.w);
        *(float4*)(o4 + m0) = rr;
    }

    // level 3 (coalesced)
    {
        const int b = tid >> 4, c = tid & 15;
        const float s1b = s1[b], s1c = s1[c];
        const float s2ab = s2[a * 16 + b];
        const float s2bc = s2[b * 16 + c];
        const float s3abc = s3[(a * 16 + b) * 16 + c];
        const float r3 = s3abc - 0.5f * fmaf(s1a, s2bc, s2ab * s1c)
                         + (1.f / 3.f) * s1a * s1b * s1c;
        outj[OFF_L3 + a * 256 + tid] = r3;
    }
    // level 2
    if (tid < 16) outj[OFF_L2 + a * 16 + tid] = fmaf(-0.5f * s1a, s1[tid], s2[a * 16 + tid]);
    // level 1
    if (tid == 0) outj[a] = s1a;
}

extern "C" void kernel_launch(void* const* d_in, const int* in_sizes, int n_in,
                              void* d_out, int out_size, void* d_ws, size_t ws_size,
                              hipStream_t stream) {
    const float* path = (const float*)d_in[0];
    float* out = (float*)d_out;
    float* ws = (float*)d_ws;
    float* dx1 = ws;
    float* dxt = ws + DXT_OFF;
    float* sig123 = ws + SIG_OFF;

    k_dx<<<NB, 256, 0, stream>>>(path, dx1, dxt);
    k_scan<<<NB * 16, 256, 0, stream>>>(dx1, dxt, out, sig123);
    k_log<<<NB * 16, 256, 0, stream>>>(sig123, out);
}